// Round 2
// baseline (445.220 us; speedup 1.0000x reference)
//
#include <hip/hip_runtime.h>
#include <hip/hip_bf16.h>
#include <math.h>

// Problem constants (setup_inputs)
#define BQ   2
#define LQ   4096
#define CQ   1024
#define NHQ  16
#define DHQ  64
#define KSEL 1638
#define KPAD 1664
#define MTOT (BQ*KSEL)   // 3276
#define MPAD 3328        // 26*128

typedef short s16x8 __attribute__((ext_vector_type(8)));
typedef float fx4   __attribute__((ext_vector_type(4)));

#define MFMA16(a,b,c) __builtin_amdgcn_mfma_f32_16x16x32_bf16(a,b,c,0,0,0)

__device__ __forceinline__ float b2f(unsigned short u) {
  union { float f; unsigned int i; } cv; cv.i = ((unsigned int)u) << 16; return cv.f;
}
__device__ __forceinline__ unsigned short f2b(float f) {
  union { float f; unsigned int i; } cv; cv.f = f;
  unsigned int x = cv.i;
  return (unsigned short)((x + 0x7fffu + ((x >> 16) & 1u)) >> 16);
}
__device__ __forceinline__ void async16(const void* g, void* l) {
  __builtin_amdgcn_global_load_lds((const __attribute__((address_space(1))) void*)g,
                                   (__attribute__((address_space(3))) void*)l, 16, 0, 0);
}

// ---------------- fp32 -> bf16 conversion (for MFMA staging) ----------------
__global__ __launch_bounds__(256) void k_cvt(const float* __restrict__ s,
                                             unsigned short* __restrict__ d, int n4) {
  int i = blockIdx.x * 256 + threadIdx.x;
  if (i < n4) {
    float4 v = ((const float4*)s)[i];
    ushort4 o;
    o.x = f2b(v.x); o.y = f2b(v.y); o.z = f2b(v.z); o.w = f2b(v.w);
    ((ushort4*)d)[i] = o;
  }
}

// ---------------- mean (fp64, 2-stage) ----------------
__global__ __launch_bounds__(256) void k_mean_part(const float* __restrict__ x,
                                                   double* __restrict__ part) {
  int bid = blockIdx.x;                    // 256 blocks: [b(2)][ch(32)][cb(4)]
  int cb = bid & 3, ch = (bid >> 2) & 31, b = bid >> 7;
  int c = cb * 256 + threadIdx.x;
  const float* p = x + ((size_t)b * LQ + (size_t)ch * 128) * CQ + c;
  double s = 0.0;
  for (int r = 0; r < 128; ++r) s += (double)p[(size_t)r * CQ];
  part[((size_t)b * 32 + ch) * CQ + c] = s;
}

__global__ __launch_bounds__(256) void k_mean_reduce(const double* __restrict__ part,
                                                     double* __restrict__ mean) {
  int g = blockIdx.x * 256 + threadIdx.x;  // 2048 = B*C
  int b = g >> 10, c = g & 1023;
  double s = 0.0;
  for (int ch = 0; ch < 32; ++ch) s += part[((size_t)b * 32 + ch) * CQ + c];
  mean[g] = s * (1.0 / 4096.0);
}

// ---------------- mse (fp64) + base output (x + upsample(cached)) ----------------
__global__ __launch_bounds__(256) void k_mse_base(const float* __restrict__ x,
                                                  const float* __restrict__ cached,
                                                  const double* __restrict__ mean,
                                                  double* __restrict__ mse,
                                                  float* __restrict__ out) {
  int bl = blockIdx.x; int b = bl >> 12, l = bl & 4095;
  int hh = l >> 6, ww = l & 63;
  size_t xoff = ((size_t)b * LQ + l) * CQ;
  size_t uoff = (((size_t)b * 32 + (hh >> 1)) * 32 + (ww >> 1)) * CQ;
  const double* mrow = mean + (size_t)b * CQ;
  int c0 = threadIdx.x * 4;
  float4 xv = *(const float4*)(x + xoff + c0);
  float4 uv = *(const float4*)(cached + uoff + c0);
  float4 ov;
  ov.x = xv.x + uv.x; ov.y = xv.y + uv.y; ov.z = xv.z + uv.z; ov.w = xv.w + uv.w;
  *(float4*)(out + xoff + c0) = ov;
  double d0 = (double)xv.x - mrow[c0];
  double d1 = (double)xv.y - mrow[c0 + 1];
  double d2 = (double)xv.z - mrow[c0 + 2];
  double d3 = (double)xv.w - mrow[c0 + 3];
  double ss = d0 * d0 + d1 * d1 + d2 * d2 + d3 * d3;
  for (int o = 1; o < 64; o <<= 1) ss += __shfl_xor(ss, o);
  __shared__ double ws4[4];
  if ((threadIdx.x & 63) == 0) ws4[threadIdx.x >> 6] = ss;
  __syncthreads();
  if (threadIdx.x == 0) mse[(size_t)b * LQ + l] = ws4[0] + ws4[1] + ws4[2] + ws4[3];
}

// ---------------- top-k: bitonic sort (desc value, asc index) ----------------
__global__ __launch_bounds__(1024) void k_topk(const double* __restrict__ mse,
                                               int* __restrict__ idx_sel) {
  __shared__ double v[4096];
  __shared__ int    id[4096];
  int b = blockIdx.x, t = threadIdx.x;
  for (int p = 0; p < 4; ++p) { int i = p * 1024 + t; v[i] = mse[(size_t)b * LQ + i]; id[i] = i; }
  __syncthreads();
  for (int k = 2; k <= 4096; k <<= 1) {
    for (int j = k >> 1; j > 0; j >>= 1) {
      for (int p = 0; p < 4; ++p) {
        int i = p * 1024 + t; int ixj = i ^ j;
        if (ixj > i) {
          bool up = ((i & k) == 0);
          double vi = v[i], vj = v[ixj]; int ii = id[i], ij = id[ixj];
          bool i_after = (vi < vj) || (vi == vj && ii > ij);  // later in (desc val, asc idx)
          if (i_after == up) { v[i] = vj; v[ixj] = vi; id[i] = ij; id[ixj] = ii; }
        }
      }
      __syncthreads();
    }
  }
  for (int base = 0; base < 2048; base += 1024) {
    int i = base + t;
    if (i < KPAD) idx_sel[b * KPAD + i] = (i < KSEL) ? id[i] : 0;
  }
}

// ---------------- GEMM (m97-style 128x128, BK=32, global_load_lds w16) ----------------
// MODE 0: A = x_bf gathered via idx_sel, B = wqkv_bf (3072x1024), C -> qkv bf16
// MODE 1: A = ob (bf16),                 B = wproj_bf (1024x1024),
//         epilogue: out[b,idx] = x + A@B^T + bproj  (fp32)
template<int MODE>
__global__ __launch_bounds__(256) void k_gemm(const unsigned short* __restrict__ Asrc,
                                              const unsigned short* __restrict__ Bmat,
                                              const int* __restrict__ idx_sel,
                                              unsigned short* __restrict__ Cbf,
                                              float* __restrict__ Cf,
                                              const float* __restrict__ xin,
                                              const float* __restrict__ bproj) {
  int bm = blockIdx.x % 26, bn = blockIdx.x / 26;
  int tid = threadIdx.x;
  int w = tid >> 6, lane = tid & 63, quad = lane >> 4, l15 = lane & 15;
  int wm = w & 1, wn = w >> 1;
  __shared__ __align__(16) unsigned char sm[16384];   // A [128][32]bf16, B [128][32]bf16

  const unsigned short* gA[2];
  const unsigned short* gB[2];
#pragma unroll
  for (int p = 0; p < 2; ++p) {
    int e = p * 256 + tid; int row = e >> 2, kc = e & 3;
    int m = bm * 128 + row; if (m >= MTOT) m = MTOT - 1;
    int bb = m / KSEL; int ii = m - bb * KSEL;
    const unsigned short* rp;
    if (MODE == 0) {
      int lsel = idx_sel[bb * KPAD + ii];
      rp = Asrc + ((size_t)bb * LQ + lsel) * CQ;
    } else {
      rp = Asrc + ((size_t)bb * KPAD + ii) * CQ;
    }
    gA[p] = rp + kc * 8;
    gB[p] = Bmat + (size_t)(bn * 128 + row) * CQ + kc * 8;
  }

  fx4 acc[4][4];
#pragma unroll
  for (int a = 0; a < 4; ++a)
#pragma unroll
    for (int c = 0; c < 4; ++c) acc[a][c] = (fx4){0.f, 0.f, 0.f, 0.f};

  for (int it = 0; it < 32; ++it) {
    int ke = it * 32;
    __syncthreads();
#pragma unroll
    for (int p = 0; p < 2; ++p) {
      async16(gA[p] + ke, sm + p * 4096 + w * 1024);
      async16(gB[p] + ke, sm + 8192 + p * 4096 + w * 1024);
    }
    __syncthreads();
    s16x8 af[4], bf[4];
#pragma unroll
    for (int mt = 0; mt < 4; ++mt)
      af[mt] = *(const s16x8*)(sm + ((wm * 64 + mt * 16 + l15) * 64 + quad * 16));
#pragma unroll
    for (int nt = 0; nt < 4; ++nt)
      bf[nt] = *(const s16x8*)(sm + 8192 + ((wn * 64 + nt * 16 + l15) * 64 + quad * 16));
#pragma unroll
    for (int mt = 0; mt < 4; ++mt)
#pragma unroll
      for (int nt = 0; nt < 4; ++nt)
        acc[mt][nt] = MFMA16(af[mt], bf[nt], acc[mt][nt]);
  }

#pragma unroll
  for (int mt = 0; mt < 4; ++mt)
#pragma unroll
    for (int nt = 0; nt < 4; ++nt) {
      int n = bn * 128 + wn * 64 + nt * 16 + l15;
      int mbase = bm * 128 + wm * 64 + mt * 16 + quad * 4;
      fx4 vv = acc[mt][nt];
      if (MODE == 0) {
#pragma unroll
        for (int r = 0; r < 4; ++r) {
          int m = mbase + r;
          if (m < MTOT) Cbf[(size_t)m * 3072 + n] = f2b(vv[r]);
        }
      } else {
        float bp = bproj[n];
#pragma unroll
        for (int r = 0; r < 4; ++r) {
          int m = mbase + r;
          if (m < MTOT) {
            int bb = m / KSEL; int ii = m - bb * KSEL;
            int lsel = idx_sel[bb * KPAD + ii];
            size_t off = ((size_t)bb * LQ + lsel) * CQ + n;
            Cf[off] = xin[off] + vv[r] + bp;
          }
        }
      }
    }
}

// ---------------- l2norm + scale + rope -> q,k ; v -> Vt (transposed) ----------------
__global__ __launch_bounds__(256) void k_normrope(const unsigned short* __restrict__ qkv,
                                                  const int* __restrict__ idx_sel,
                                                  const float* __restrict__ qbias,
                                                  const float* __restrict__ vbias,
                                                  const float* __restrict__ sml,
                                                  const float* __restrict__ rope,
                                                  unsigned short* __restrict__ qo,
                                                  unsigned short* __restrict__ ko,
                                                  unsigned short* __restrict__ vt) {
  int bid = blockIdx.x;                       // 26*16*2
  int tile = bid % 26; int h = (bid / 26) & 15; int b = bid / (26 * 16);
  int tid = threadIdx.x; int w = tid >> 6; int d = tid & 63;
  __shared__ unsigned short vtile[64 * 68];
  float scale = expf(fminf(sml[h], 4.6051702f));
  float qb = qbias[h * 64 + d];
  float vb = vbias[h * 64 + d];
  for (int pass = 0; pass < 16; ++pass) {
    int il = pass * 4 + w;
    int i = tile * 64 + il;
    float vraw = 0.f;
    if (i < KSEL) {
      int lsel = idx_sel[b * KPAD + i];
      size_t base = ((size_t)(b * KSEL + i)) * 3072 + h * 64 + d;
      int tt = d >> 1;
      float r0 = rope[(size_t)lsel * 32 + tt];
      float r1 = rope[(size_t)LQ * 32 + (size_t)lsel * 32 + tt];
      // q
      float qv = b2f(qkv[base]) + qb;
      float ss = qv * qv;
      for (int o = 1; o < 64; o <<= 1) ss += __shfl_xor(ss, o);
      float qn = qv / fmaxf(sqrtf(ss), 1e-12f) * scale;
      float qp = __shfl_xor(qn, 1);
      float qr = (d & 1) ? (r1 * qp + r0 * qn) : (r0 * qn - r1 * qp);
      qo[((size_t)(b * NHQ + h) * KPAD + i) * 64 + d] = f2b(qr);
      // k
      float kv = b2f(qkv[base + 1024]);
      float ks = kv * kv;
      for (int o = 1; o < 64; o <<= 1) ks += __shfl_xor(ks, o);
      float kn = kv / fmaxf(sqrtf(ks), 1e-12f);
      float kp = __shfl_xor(kn, 1);
      float kr = (d & 1) ? (r1 * kp + r0 * kn) : (r0 * kn - r1 * kp);
      ko[((size_t)(b * NHQ + h) * KPAD + i) * 64 + d] = f2b(kr);
      vraw = b2f(qkv[base + 2048]) + vb;
    }
    vtile[d * 68 + il] = f2b(vraw);
  }
  __syncthreads();
  int row = tid >> 2, c0 = (tid & 3) * 16;
  s16x8 o0, o1;
#pragma unroll
  for (int jj = 0; jj < 8; ++jj) {
    o0[jj] = (short)vtile[row * 68 + c0 + jj];
    o1[jj] = (short)vtile[row * 68 + c0 + 8 + jj];
  }
  size_t doff = ((size_t)((b * NHQ + h) * 64 + row)) * KPAD + (size_t)tile * 64 + c0;
  *(s16x8*)(vt + doff) = o0;
  *(s16x8*)(vt + doff + 8) = o1;
}

// ---------------- flash attention over the 1638 selected tokens ----------------
__global__ __launch_bounds__(256) void k_attn(const unsigned short* __restrict__ qb,
                                              const unsigned short* __restrict__ kb,
                                              const unsigned short* __restrict__ vtb,
                                              unsigned short* __restrict__ ob) {
  int qt = blockIdx.x; int bh = blockIdx.y; int b = bh >> 4, h = bh & 15;
  int q0 = qt * 128;
  int tid = threadIdx.x, w = tid >> 6, lane = tid & 63, quad = lane >> 4, l15 = lane & 15;
  __shared__ __align__(16) unsigned char sm[34816 + 17408];
  unsigned char* Pk = sm;            // K-tile [128][72]bf16  (phase 1) / P [128][136]bf16 (phase 2)
  unsigned char* Vt = sm + 34816;    // Vt-tile [64][136]bf16
  const unsigned short* qbase = qb + (size_t)(b * NHQ + h) * KPAD * 64;
  const unsigned short* kbase = kb + (size_t)(b * NHQ + h) * KPAD * 64;
  const unsigned short* vbase = vtb + (size_t)(b * NHQ + h) * 64 * KPAD;

  s16x8 qf[2][2];
#pragma unroll
  for (int mi = 0; mi < 2; ++mi)
#pragma unroll
    for (int s = 0; s < 2; ++s) {
      int row = q0 + w * 32 + mi * 16 + l15;
      qf[mi][s] = *(const s16x8*)(qbase + (size_t)row * 64 + s * 32 + quad * 8);
    }

  float m_st[2][4], l_st[2][4];
  fx4 oacc[2][4];
#pragma unroll
  for (int mi = 0; mi < 2; ++mi)
#pragma unroll
    for (int r = 0; r < 4; ++r) { m_st[mi][r] = -1e30f; l_st[mi][r] = 0.f; }
#pragma unroll
  for (int mi = 0; mi < 2; ++mi)
#pragma unroll
    for (int dt = 0; dt < 4; ++dt) oacc[mi][dt] = (fx4){0.f, 0.f, 0.f, 0.f};

  for (int t = 0; t < 13; ++t) {
    int j0 = t * 128;
    __syncthreads();  // protect previous iteration's P/Vt reads
#pragma unroll
    for (int p = 0; p < 4; ++p) {   // K-tile: 128 rows x 64 d
      int e = p * 256 + tid; int row = e >> 3, kc = e & 7;
      *(s16x8*)(Pk + row * 144 + kc * 16) =
          *(const s16x8*)(kbase + (size_t)(j0 + row) * 64 + kc * 8);
    }
#pragma unroll
    for (int p = 0; p < 4; ++p) {   // Vt-tile: 64 rows x 128 tokens
      int e = p * 256 + tid; int row = e >> 4, tc = e & 15;
      *(s16x8*)(Vt + row * 272 + tc * 16) =
          *(const s16x8*)(vbase + (size_t)row * KPAD + j0 + tc * 8);
    }
    __syncthreads();

    // S = Q K^T
    fx4 sacc[2][8];
#pragma unroll
    for (int mi = 0; mi < 2; ++mi)
#pragma unroll
      for (int nj = 0; nj < 8; ++nj) sacc[mi][nj] = (fx4){0.f, 0.f, 0.f, 0.f};
#pragma unroll
    for (int nj = 0; nj < 8; ++nj) {
      s16x8 kf0 = *(const s16x8*)(Pk + (nj * 16 + l15) * 144 + quad * 16);
      s16x8 kf1 = *(const s16x8*)(Pk + (nj * 16 + l15) * 144 + 64 + quad * 16);
      sacc[0][nj] = MFMA16(qf[0][0], kf0, sacc[0][nj]);
      sacc[1][nj] = MFMA16(qf[1][0], kf0, sacc[1][nj]);
      sacc[0][nj] = MFMA16(qf[0][1], kf1, sacc[0][nj]);
      sacc[1][nj] = MFMA16(qf[1][1], kf1, sacc[1][nj]);
    }

    // online softmax (in registers)
    float alpha[2][4];
#pragma unroll
    for (int mi = 0; mi < 2; ++mi)
#pragma unroll
      for (int r = 0; r < 4; ++r) {
        float mx = -1e30f;
#pragma unroll
        for (int nj = 0; nj < 8; ++nj) {
          int jg = j0 + nj * 16 + l15;
          if (jg < KSEL) mx = fmaxf(mx, sacc[mi][nj][r]);
        }
        for (int o = 1; o < 16; o <<= 1) mx = fmaxf(mx, __shfl_xor(mx, o));
        float mn = fmaxf(m_st[mi][r], mx);
        float al = expf(m_st[mi][r] - mn);
        float s = 0.f;
#pragma unroll
        for (int nj = 0; nj < 8; ++nj) {
          int jg = j0 + nj * 16 + l15;
          float p = (jg < KSEL) ? expf(sacc[mi][nj][r] - mn) : 0.f;
          sacc[mi][nj][r] = p; s += p;
        }
        for (int o = 1; o < 16; o <<= 1) s += __shfl_xor(s, o);
        m_st[mi][r] = mn; l_st[mi][r] = l_st[mi][r] * al + s;
        alpha[mi][r] = al;
      }
    __syncthreads();  // everyone done reading K-tile
    // write P (bf16) into the K/P union buffer
#pragma unroll
    for (int mi = 0; mi < 2; ++mi)
#pragma unroll
      for (int nj = 0; nj < 8; ++nj) {
        int col = nj * 16 + l15;
#pragma unroll
        for (int r = 0; r < 4; ++r) {
          int row = w * 32 + mi * 16 + quad * 4 + r;
          *(unsigned short*)(Pk + row * 272 + col * 2) = f2b(sacc[mi][nj][r]);
        }
      }
    __syncthreads();

    // O = O*alpha + P V
#pragma unroll
    for (int mi = 0; mi < 2; ++mi)
#pragma unroll
      for (int dt = 0; dt < 4; ++dt) {
        fx4 oo = oacc[mi][dt];
#pragma unroll
        for (int r = 0; r < 4; ++r) oo[r] *= alpha[mi][r];
        oacc[mi][dt] = oo;
      }
#pragma unroll
    for (int js = 0; js < 4; ++js) {
      s16x8 vf[4];
#pragma unroll
      for (int dt = 0; dt < 4; ++dt)
        vf[dt] = *(const s16x8*)(Vt + (dt * 16 + l15) * 272 + js * 64 + quad * 16);
#pragma unroll
      for (int mi = 0; mi < 2; ++mi) {
        s16x8 pf = *(const s16x8*)(Pk + (w * 32 + mi * 16 + l15) * 272 + js * 64 + quad * 16);
#pragma unroll
        for (int dt = 0; dt < 4; ++dt)
          oacc[mi][dt] = MFMA16(pf, vf[dt], oacc[mi][dt]);
      }
    }
  }

#pragma unroll
  for (int mi = 0; mi < 2; ++mi)
#pragma unroll
    for (int dt = 0; dt < 4; ++dt)
#pragma unroll
      for (int r = 0; r < 4; ++r) {
        int gq = q0 + w * 32 + mi * 16 + quad * 4 + r;
        if (gq < KSEL) {
          float val = oacc[mi][dt][r] / l_st[mi][r];
          ob[((size_t)(b * KPAD + gq)) * CQ + h * 64 + dt * 16 + l15] = f2b(val);
        }
      }
}

extern "C" void kernel_launch(void* const* d_in, const int* in_sizes, int n_in,
                              void* d_out, int out_size, void* d_ws, size_t ws_size,
                              hipStream_t stream) {
  const float* x      = (const float*)d_in[0];
  const float* cached = (const float*)d_in[1];
  const float* wqkv   = (const float*)d_in[2];
  const float* qbias  = (const float*)d_in[3];
  const float* vbias  = (const float*)d_in[4];
  const float* wproj  = (const float*)d_in[5];
  const float* bproj  = (const float*)d_in[6];
  const float* sml    = (const float*)d_in[7];
  const float* rope   = (const float*)d_in[8];
  float* out = (float*)d_out;
  char* ws = (char*)d_ws;

  double* meanpart        = (double*)(ws);                    // 524288
  double* mean            = (double*)(ws + 524288);           // 16384
  double* mse             = (double*)(ws + 540672);           // 65536
  int* idx_sel            = (int*)(ws + 606208);              // 13312
  unsigned short* x_bf    = (unsigned short*)(ws + 619520);   // 16777216
  unsigned short* wqkv_bf = (unsigned short*)(ws + 17396736); // 6291456
  unsigned short* wproj_bf= (unsigned short*)(ws + 23688192); // 2097152
  unsigned short* qkv     = (unsigned short*)(ws + 25785344); // 20447232
  unsigned short* qo      = (unsigned short*)(ws + 46232576); // 6815744
  unsigned short* ko      = (unsigned short*)(ws + 53048320); // 6815744
  unsigned short* vt      = (unsigned short*)(ws + 59864064); // 6815744
  unsigned short* ob      = (unsigned short*)(ws + 66679808); // 6815744 -> end 73495552

  hipLaunchKernelGGL(k_cvt, dim3(8192), dim3(256), 0, stream, x, x_bf, LQ * CQ * BQ / 4);
  hipLaunchKernelGGL(k_cvt, dim3(3072), dim3(256), 0, stream, wqkv, wqkv_bf, 3072 * CQ / 4);
  hipLaunchKernelGGL(k_cvt, dim3(1024), dim3(256), 0, stream, wproj, wproj_bf, CQ * CQ / 4);
  hipLaunchKernelGGL(k_mean_part, dim3(256), dim3(256), 0, stream, x, meanpart);
  hipLaunchKernelGGL(k_mean_reduce, dim3(8), dim3(256), 0, stream, meanpart, mean);
  hipLaunchKernelGGL(k_mse_base, dim3(8192), dim3(256), 0, stream, x, cached, mean, mse, out);
  hipLaunchKernelGGL(k_topk, dim3(BQ), dim3(1024), 0, stream, mse, idx_sel);
  hipLaunchKernelGGL((k_gemm<0>), dim3(26 * 24), dim3(256), 0, stream,
                     x_bf, wqkv_bf, idx_sel, qkv, (float*)nullptr,
                     (const float*)nullptr, (const float*)nullptr);
  hipLaunchKernelGGL(k_normrope, dim3(26 * 16 * BQ), dim3(256), 0, stream,
                     qkv, idx_sel, qbias, vbias, sml, rope, qo, ko, vt);
  hipLaunchKernelGGL(k_attn, dim3(13, BQ * NHQ), dim3(256), 0, stream, qo, ko, vt, ob);
  hipLaunchKernelGGL((k_gemm<1>), dim3(26 * 8), dim3(256), 0, stream,
                     ob, wproj_bf, idx_sel, (unsigned short*)nullptr, out, x, bproj);
}

// Round 3
// 393.737 us; speedup vs baseline: 1.1308x; 1.1308x over previous
//
#include <hip/hip_runtime.h>
#include <hip/hip_bf16.h>
#include <math.h>

// Problem constants (setup_inputs)
#define BQ   2
#define LQ   4096
#define CQ   1024
#define NHQ  16
#define DHQ  64
#define KSEL 1638
#define KPAD 1664
#define MTOT (BQ*KSEL)   // 3276
#define MPAD 3328        // 26*128

typedef short s16x8 __attribute__((ext_vector_type(8)));
typedef float fx4   __attribute__((ext_vector_type(4)));

#define MFMA16(a,b,c) __builtin_amdgcn_mfma_f32_16x16x32_bf16(a,b,c,0,0,0)

__device__ __forceinline__ float b2f(unsigned short u) {
  union { float f; unsigned int i; } cv; cv.i = ((unsigned int)u) << 16; return cv.f;
}
__device__ __forceinline__ unsigned short f2b(float f) {
  union { float f; unsigned int i; } cv; cv.f = f;
  unsigned int x = cv.i;
  return (unsigned short)((x + 0x7fffu + ((x >> 16) & 1u)) >> 16);
}
__device__ __forceinline__ unsigned short f2b_trunc(float f) {
  union { float f; unsigned int i; } cv; cv.f = f;
  return (unsigned short)(cv.i >> 16);
}
__device__ __forceinline__ void async16(const void* g, void* l) {
  __builtin_amdgcn_global_load_lds((const __attribute__((address_space(1))) void*)g,
                                   (__attribute__((address_space(3))) void*)l, 16, 0, 0);
}

// ---------------- fp32 -> bf16 conversion, fused over x / W_qkv / W_proj ----------------
__global__ __launch_bounds__(256) void k_cvt3(const float* __restrict__ x,
                                              const float* __restrict__ wqkv,
                                              const float* __restrict__ wproj,
                                              unsigned short* __restrict__ xb,
                                              unsigned short* __restrict__ wqb,
                                              unsigned short* __restrict__ wpb) {
  int i = blockIdx.x * 256 + threadIdx.x;   // float4 index, total 3145728
  const float* s; unsigned short* d; int off;
  if (i < 2097152)      { s = x;     d = xb;  off = i; }
  else if (i < 2883584) { s = wqkv;  d = wqb; off = i - 2097152; }
  else                  { s = wproj; d = wpb; off = i - 2883584; }
  float4 v = ((const float4*)s)[off];
  ushort4 o;
  o.x = f2b(v.x); o.y = f2b(v.y); o.z = f2b(v.z); o.w = f2b(v.w);
  ((ushort4*)d)[off] = o;
}

// ---------------- mean (fp64, 2-stage) ----------------
__global__ __launch_bounds__(256) void k_mean_part(const float* __restrict__ x,
                                                   double* __restrict__ part) {
  int bid = blockIdx.x;                    // 256 blocks: [b(2)][ch(32)][cb(4)]
  int cb = bid & 3, ch = (bid >> 2) & 31, b = bid >> 7;
  int c = cb * 256 + threadIdx.x;
  const float* p = x + ((size_t)b * LQ + (size_t)ch * 128) * CQ + c;
  double s = 0.0;
  for (int r = 0; r < 128; ++r) s += (double)p[(size_t)r * CQ];
  part[((size_t)b * 32 + ch) * CQ + c] = s;
}

__global__ __launch_bounds__(256) void k_mean_reduce(const double* __restrict__ part,
                                                     double* __restrict__ mean) {
  int g = blockIdx.x * 256 + threadIdx.x;  // 2048 = B*C
  int b = g >> 10, c = g & 1023;
  double s = 0.0;
  for (int ch = 0; ch < 32; ++ch) s += part[((size_t)b * 32 + ch) * CQ + c];
  mean[g] = s * (1.0 / 4096.0);
}

// ---------------- mse (fp64) + base output (x + upsample(cached)) ----------------
__global__ __launch_bounds__(256) void k_mse_base(const float* __restrict__ x,
                                                  const float* __restrict__ cached,
                                                  const double* __restrict__ mean,
                                                  double* __restrict__ mse,
                                                  float* __restrict__ out) {
  int bl = blockIdx.x; int b = bl >> 12, l = bl & 4095;
  int hh = l >> 6, ww = l & 63;
  size_t xoff = ((size_t)b * LQ + l) * CQ;
  size_t uoff = (((size_t)b * 32 + (hh >> 1)) * 32 + (ww >> 1)) * CQ;
  const double* mrow = mean + (size_t)b * CQ;
  int c0 = threadIdx.x * 4;
  float4 xv = *(const float4*)(x + xoff + c0);
  float4 uv = *(const float4*)(cached + uoff + c0);
  float4 ov;
  ov.x = xv.x + uv.x; ov.y = xv.y + uv.y; ov.z = xv.z + uv.z; ov.w = xv.w + uv.w;
  *(float4*)(out + xoff + c0) = ov;
  double d0 = (double)xv.x - mrow[c0];
  double d1 = (double)xv.y - mrow[c0 + 1];
  double d2 = (double)xv.z - mrow[c0 + 2];
  double d3 = (double)xv.w - mrow[c0 + 3];
  double ss = d0 * d0 + d1 * d1 + d2 * d2 + d3 * d3;
  for (int o = 1; o < 64; o <<= 1) ss += __shfl_xor(ss, o);
  __shared__ double ws4[4];
  if ((threadIdx.x & 63) == 0) ws4[threadIdx.x >> 6] = ss;
  __syncthreads();
  if (threadIdx.x == 0) mse[(size_t)b * LQ + l] = ws4[0] + ws4[1] + ws4[2] + ws4[3];
}

// ---------------- top-k: bitonic sort (desc value, asc index) ----------------
__global__ __launch_bounds__(1024) void k_topk(const double* __restrict__ mse,
                                               int* __restrict__ idx_sel) {
  __shared__ double v[4096];
  __shared__ int    id[4096];
  int b = blockIdx.x, t = threadIdx.x;
  for (int p = 0; p < 4; ++p) { int i = p * 1024 + t; v[i] = mse[(size_t)b * LQ + i]; id[i] = i; }
  __syncthreads();
  for (int k = 2; k <= 4096; k <<= 1) {
    for (int j = k >> 1; j > 0; j >>= 1) {
      for (int p = 0; p < 4; ++p) {
        int i = p * 1024 + t; int ixj = i ^ j;
        if (ixj > i) {
          bool up = ((i & k) == 0);
          double vi = v[i], vj = v[ixj]; int ii = id[i], ij = id[ixj];
          bool i_after = (vi < vj) || (vi == vj && ii > ij);  // later in (desc val, asc idx)
          if (i_after == up) { v[i] = vj; v[ixj] = vi; id[i] = ij; id[ixj] = ii; }
        }
      }
      __syncthreads();
    }
  }
  for (int base = 0; base < 2048; base += 1024) {
    int i = base + t;
    if (i < KPAD) idx_sel[b * KPAD + i] = (i < KSEL) ? id[i] : 0;
  }
}

// ---------------- GEMM (m97-style 128x128, BK=32, global_load_lds w16) ----------------
// MODE 0: A = x_bf gathered via idx_sel, B = wqkv_bf (3072x1024), C -> qkv bf16
// MODE 1: A = ob (bf16),                 B = wproj_bf (1024x1024),
//         epilogue: out[b,idx] = x + A@B^T + bproj  (fp32)
template<int MODE>
__global__ __launch_bounds__(256) void k_gemm(const unsigned short* __restrict__ Asrc,
                                              const unsigned short* __restrict__ Bmat,
                                              const int* __restrict__ idx_sel,
                                              unsigned short* __restrict__ Cbf,
                                              float* __restrict__ Cf,
                                              const float* __restrict__ xin,
                                              const float* __restrict__ bproj) {
  int bm = blockIdx.x % 26, bn = blockIdx.x / 26;
  int tid = threadIdx.x;
  int w = tid >> 6, lane = tid & 63, quad = lane >> 4, l15 = lane & 15;
  int wm = w & 1, wn = w >> 1;
  __shared__ __align__(16) unsigned char sm[16384];   // A [128][32]bf16, B [128][32]bf16

  const unsigned short* gA[2];
  const unsigned short* gB[2];
#pragma unroll
  for (int p = 0; p < 2; ++p) {
    int e = p * 256 + tid; int row = e >> 2, kc = e & 3;
    int m = bm * 128 + row; if (m >= MTOT) m = MTOT - 1;
    int bb = m / KSEL; int ii = m - bb * KSEL;
    const unsigned short* rp;
    if (MODE == 0) {
      int lsel = idx_sel[bb * KPAD + ii];
      rp = Asrc + ((size_t)bb * LQ + lsel) * CQ;
    } else {
      rp = Asrc + ((size_t)bb * KPAD + ii) * CQ;
    }
    gA[p] = rp + kc * 8;
    gB[p] = Bmat + (size_t)(bn * 128 + row) * CQ + kc * 8;
  }

  fx4 acc[4][4];
#pragma unroll
  for (int a = 0; a < 4; ++a)
#pragma unroll
    for (int c = 0; c < 4; ++c) acc[a][c] = (fx4){0.f, 0.f, 0.f, 0.f};

  for (int it = 0; it < 32; ++it) {
    int ke = it * 32;
    __syncthreads();
#pragma unroll
    for (int p = 0; p < 2; ++p) {
      async16(gA[p] + ke, sm + p * 4096 + w * 1024);
      async16(gB[p] + ke, sm + 8192 + p * 4096 + w * 1024);
    }
    __syncthreads();
    s16x8 af[4], bf[4];
#pragma unroll
    for (int mt = 0; mt < 4; ++mt)
      af[mt] = *(const s16x8*)(sm + ((wm * 64 + mt * 16 + l15) * 64 + quad * 16));
#pragma unroll
    for (int nt = 0; nt < 4; ++nt)
      bf[nt] = *(const s16x8*)(sm + 8192 + ((wn * 64 + nt * 16 + l15) * 64 + quad * 16));
#pragma unroll
    for (int mt = 0; mt < 4; ++mt)
#pragma unroll
      for (int nt = 0; nt < 4; ++nt)
        acc[mt][nt] = MFMA16(af[mt], bf[nt], acc[mt][nt]);
  }

#pragma unroll
  for (int mt = 0; mt < 4; ++mt)
#pragma unroll
    for (int nt = 0; nt < 4; ++nt) {
      int n = bn * 128 + wn * 64 + nt * 16 + l15;
      int mbase = bm * 128 + wm * 64 + mt * 16 + quad * 4;
      fx4 vv = acc[mt][nt];
      if (MODE == 0) {
#pragma unroll
        for (int r = 0; r < 4; ++r) {
          int m = mbase + r;
          if (m < MTOT) Cbf[(size_t)m * 3072 + n] = f2b(vv[r]);
        }
      } else {
        float bp = bproj[n];
#pragma unroll
        for (int r = 0; r < 4; ++r) {
          int m = mbase + r;
          if (m < MTOT) {
            int bb = m / KSEL; int ii = m - bb * KSEL;
            int lsel = idx_sel[bb * KPAD + ii];
            size_t off = ((size_t)bb * LQ + lsel) * CQ + n;
            Cf[off] = xin[off] + vv[r] + bp;
          }
        }
      }
    }
}

// ---------------- l2norm + scale + rope -> q,k ; v -> Vt (transposed) ----------------
__global__ __launch_bounds__(256) void k_normrope(const unsigned short* __restrict__ qkv,
                                                  const int* __restrict__ idx_sel,
                                                  const float* __restrict__ qbias,
                                                  const float* __restrict__ vbias,
                                                  const float* __restrict__ sml,
                                                  const float* __restrict__ rope,
                                                  unsigned short* __restrict__ qo,
                                                  unsigned short* __restrict__ ko,
                                                  unsigned short* __restrict__ vt) {
  int bid = blockIdx.x;                       // 26*16*2
  int tile = bid % 26; int h = (bid / 26) & 15; int b = bid / (26 * 16);
  int tid = threadIdx.x; int w = tid >> 6; int d = tid & 63;
  __shared__ unsigned short vtile[64 * 68];
  float scale = expf(fminf(sml[h], 4.6051702f));
  float qb = qbias[h * 64 + d];
  float vb = vbias[h * 64 + d];
  for (int pass = 0; pass < 16; ++pass) {
    int il = pass * 4 + w;
    int i = tile * 64 + il;
    float vraw = 0.f;
    if (i < KSEL) {
      int lsel = idx_sel[b * KPAD + i];
      size_t base = ((size_t)(b * KSEL + i)) * 3072 + h * 64 + d;
      int tt = d >> 1;
      float r0 = rope[(size_t)lsel * 32 + tt];
      float r1 = rope[(size_t)LQ * 32 + (size_t)lsel * 32 + tt];
      // q
      float qv = b2f(qkv[base]) + qb;
      float ss = qv * qv;
      for (int o = 1; o < 64; o <<= 1) ss += __shfl_xor(ss, o);
      float qn = qv / fmaxf(sqrtf(ss), 1e-12f) * scale;
      float qp = __shfl_xor(qn, 1);
      float qr = (d & 1) ? (r1 * qp + r0 * qn) : (r0 * qn - r1 * qp);
      qo[((size_t)(b * NHQ + h) * KPAD + i) * 64 + d] = f2b(qr);
      // k
      float kv = b2f(qkv[base + 1024]);
      float ks = kv * kv;
      for (int o = 1; o < 64; o <<= 1) ks += __shfl_xor(ks, o);
      float kn = kv / fmaxf(sqrtf(ks), 1e-12f);
      float kp = __shfl_xor(kn, 1);
      float kr = (d & 1) ? (r1 * kp + r0 * kn) : (r0 * kn - r1 * kp);
      ko[((size_t)(b * NHQ + h) * KPAD + i) * 64 + d] = f2b(kr);
      vraw = b2f(qkv[base + 2048]) + vb;
    }
    vtile[d * 68 + il] = f2b(vraw);
  }
  __syncthreads();
  int row = tid >> 2, c0 = (tid & 3) * 16;
  s16x8 o0, o1;
#pragma unroll
  for (int jj = 0; jj < 8; ++jj) {
    o0[jj] = (short)vtile[row * 68 + c0 + jj];
    o1[jj] = (short)vtile[row * 68 + c0 + 8 + jj];
  }
  size_t doff = ((size_t)((b * NHQ + h) * 64 + row)) * KPAD + (size_t)tile * 64 + c0;
  *(s16x8*)(vt + doff) = o0;
  *(s16x8*)(vt + doff + 8) = o1;
}

// ---------------- flash attention, fixed-max softmax, j-split x2 ----------------
// part p handles K-tiles [p?7:0 .. p?13:7); writes unnormalized O (bf16) + row-sum l (f32)
__global__ __launch_bounds__(256) void k_attn(const unsigned short* __restrict__ qb,
                                              const unsigned short* __restrict__ kb,
                                              const unsigned short* __restrict__ vtb,
                                              const float* __restrict__ sml,
                                              unsigned short* __restrict__ pO,
                                              float* __restrict__ pl) {
  int qt = blockIdx.x; int bh = blockIdx.y; int part = blockIdx.z;
  int b = bh >> 4, h = bh & 15;
  int t0 = part ? 7 : 0, t1 = part ? 13 : 7;
  int q0 = qt * 128;
  int tid = threadIdx.x, w = tid >> 6, lane = tid & 63, quad = lane >> 4, l15 = lane & 15;
  float M = __expf(fminf(sml[h], 4.6051702f));   // |S| <= scale, use as softmax shift
  __shared__ __align__(16) unsigned char sm[34816 + 17408];
  unsigned char* Pk = sm;            // K-tile [128][72]bf16 (phase 1) / P [128][136]bf16 (phase 2)
  unsigned char* Vt = sm + 34816;    // Vt-tile [64][136]bf16
  const unsigned short* qbase = qb + (size_t)(b * NHQ + h) * KPAD * 64;
  const unsigned short* kbase = kb + (size_t)(b * NHQ + h) * KPAD * 64;
  const unsigned short* vbase = vtb + (size_t)(b * NHQ + h) * 64 * KPAD;

  s16x8 qf[2][2];
#pragma unroll
  for (int mi = 0; mi < 2; ++mi)
#pragma unroll
    for (int s = 0; s < 2; ++s) {
      int row = q0 + w * 32 + mi * 16 + l15;
      qf[mi][s] = *(const s16x8*)(qbase + (size_t)row * 64 + s * 32 + quad * 8);
    }

  float lsum[2][4];
  fx4 oacc[2][4];
#pragma unroll
  for (int mi = 0; mi < 2; ++mi)
#pragma unroll
    for (int r = 0; r < 4; ++r) lsum[mi][r] = 0.f;
#pragma unroll
  for (int mi = 0; mi < 2; ++mi)
#pragma unroll
    for (int dt = 0; dt < 4; ++dt) oacc[mi][dt] = (fx4){0.f, 0.f, 0.f, 0.f};

  for (int t = t0; t < t1; ++t) {
    int j0 = t * 128;
    __syncthreads();  // protect previous iteration's P/Vt reads
#pragma unroll
    for (int p = 0; p < 4; ++p) {   // K-tile: 128 rows x 64 d
      int e = p * 256 + tid; int row = e >> 3, kc = e & 7;
      *(s16x8*)(Pk + row * 144 + kc * 16) =
          *(const s16x8*)(kbase + (size_t)(j0 + row) * 64 + kc * 8);
    }
#pragma unroll
    for (int p = 0; p < 4; ++p) {   // Vt-tile: 64 rows x 128 tokens
      int e = p * 256 + tid; int row = e >> 4, tc = e & 15;
      *(s16x8*)(Vt + row * 272 + tc * 16) =
          *(const s16x8*)(vbase + (size_t)row * KPAD + j0 + tc * 8);
    }
    __syncthreads();

    // S = Q K^T
    fx4 sacc[2][8];
#pragma unroll
    for (int mi = 0; mi < 2; ++mi)
#pragma unroll
      for (int nj = 0; nj < 8; ++nj) sacc[mi][nj] = (fx4){0.f, 0.f, 0.f, 0.f};
#pragma unroll
    for (int nj = 0; nj < 8; ++nj) {
      s16x8 kf0 = *(const s16x8*)(Pk + (nj * 16 + l15) * 144 + quad * 16);
      s16x8 kf1 = *(const s16x8*)(Pk + (nj * 16 + l15) * 144 + 64 + quad * 16);
      sacc[0][nj] = MFMA16(qf[0][0], kf0, sacc[0][nj]);
      sacc[1][nj] = MFMA16(qf[1][0], kf0, sacc[1][nj]);
      sacc[0][nj] = MFMA16(qf[0][1], kf1, sacc[0][nj]);
      sacc[1][nj] = MFMA16(qf[1][1], kf1, sacc[1][nj]);
    }

    // P = exp(S - M); accumulate row sums in registers (no online max needed)
    bool tail = (j0 + 128 > KSEL);
#pragma unroll
    for (int mi = 0; mi < 2; ++mi)
#pragma unroll
      for (int nj = 0; nj < 8; ++nj) {
        fx4 sv = sacc[mi][nj];
#pragma unroll
        for (int r = 0; r < 4; ++r) {
          float p = __expf(sv[r] - M);
          sv[r] = p;
        }
        if (tail) {
          int jg = j0 + nj * 16 + l15;
          if (jg >= KSEL) { sv[0] = 0.f; sv[1] = 0.f; sv[2] = 0.f; sv[3] = 0.f; }
        }
#pragma unroll
        for (int r = 0; r < 4; ++r) lsum[mi][r] += sv[r];
        sacc[mi][nj] = sv;
      }
    __syncthreads();  // everyone done reading K-tile
#pragma unroll
    for (int mi = 0; mi < 2; ++mi)
#pragma unroll
      for (int nj = 0; nj < 8; ++nj) {
        int col = nj * 16 + l15;
#pragma unroll
        for (int r = 0; r < 4; ++r) {
          int row = w * 32 + mi * 16 + quad * 4 + r;
          *(unsigned short*)(Pk + row * 272 + col * 2) = f2b_trunc(sacc[mi][nj][r]);
        }
      }
    __syncthreads();

    // O += P V (no rescale: fixed max)
#pragma unroll
    for (int js = 0; js < 4; ++js) {
      s16x8 vf[4];
#pragma unroll
      for (int dt = 0; dt < 4; ++dt)
        vf[dt] = *(const s16x8*)(Vt + (dt * 16 + l15) * 272 + js * 64 + quad * 16);
#pragma unroll
      for (int mi = 0; mi < 2; ++mi) {
        s16x8 pf = *(const s16x8*)(Pk + (w * 32 + mi * 16 + l15) * 272 + js * 64 + quad * 16);
#pragma unroll
        for (int dt = 0; dt < 4; ++dt)
          oacc[mi][dt] = MFMA16(pf, vf[dt], oacc[mi][dt]);
      }
    }
  }

  // reduce row sums across the 16 lanes holding each row's columns
#pragma unroll
  for (int mi = 0; mi < 2; ++mi)
#pragma unroll
    for (int r = 0; r < 4; ++r) {
      float s = lsum[mi][r];
      for (int o = 1; o < 16; o <<= 1) s += __shfl_xor(s, o);
      lsum[mi][r] = s;
    }

  size_t pbase = (((size_t)part * 2 + b) * NHQ + h) * KPAD;
#pragma unroll
  for (int mi = 0; mi < 2; ++mi)
#pragma unroll
    for (int r = 0; r < 4; ++r) {
      int gq = q0 + w * 32 + mi * 16 + quad * 4 + r;
#pragma unroll
      for (int dt = 0; dt < 4; ++dt)
        pO[(pbase + gq) * 64 + dt * 16 + l15] = f2b(oacc[mi][dt][r]);
      if (l15 == 0) pl[pbase + gq] = lsum[mi][r];
    }
}

// ---------------- combine the two j-halves: o = (Oa+Ob)/(la+lb) -> ob (bf16) ----------------
__global__ __launch_bounds__(256) void k_comb(const unsigned short* __restrict__ pO,
                                              const float* __restrict__ pl,
                                              unsigned short* __restrict__ ob) {
  size_t g = (size_t)blockIdx.x * 256 + threadIdx.x;   // 2*16*1664*64 = 3407872
  int d = (int)(g & 63);
  size_t row = g >> 6;              // (b*16+h)*1664 + gq
  int gq = (int)(row % KPAD);
  int bhh = (int)(row / KPAD);
  int b = bhh >> 4, h = bhh & 15;
  float oa = b2f(pO[g]);
  float obv = b2f(pO[g + 3407872]);
  float la = pl[row], lb = pl[row + 53248];
  float o = (oa + obv) / (la + lb);
  ob[((size_t)(b * KPAD + gq)) * CQ + h * 64 + d] = f2b(o);
}

extern "C" void kernel_launch(void* const* d_in, const int* in_sizes, int n_in,
                              void* d_out, int out_size, void* d_ws, size_t ws_size,
                              hipStream_t stream) {
  const float* x      = (const float*)d_in[0];
  const float* cached = (const float*)d_in[1];
  const float* wqkv   = (const float*)d_in[2];
  const float* qbias  = (const float*)d_in[3];
  const float* vbias  = (const float*)d_in[4];
  const float* wproj  = (const float*)d_in[5];
  const float* bproj  = (const float*)d_in[6];
  const float* sml    = (const float*)d_in[7];
  const float* rope   = (const float*)d_in[8];
  float* out = (float*)d_out;
  char* ws = (char*)d_ws;

  double* meanpart        = (double*)(ws);                    // 524288
  double* mean            = (double*)(ws + 524288);           // 16384
  double* mse             = (double*)(ws + 540672);           // 65536
  int* idx_sel            = (int*)(ws + 606208);              // 13312 -> 619520
  // overlap zone [619520, 44135424): x_bf + wqkv_bf + qkv (dead after k_normrope)
  unsigned short* x_bf    = (unsigned short*)(ws + 619520);   // 16777216
  unsigned short* wqkv_bf = (unsigned short*)(ws + 17396736); // 6291456
  unsigned short* qkv     = (unsigned short*)(ws + 23688192); // 20447232 -> 44135424
  // attn partials reuse the dead x_bf region
  unsigned short* pO      = (unsigned short*)(ws + 619520);   // 13631488
  float* pl               = (float*)(ws + 14251008);          // 425984 -> 14676992
  unsigned short* wproj_bf= (unsigned short*)(ws + 44135424); // 2097152
  unsigned short* qo      = (unsigned short*)(ws + 46232576); // 6815744
  unsigned short* ko      = (unsigned short*)(ws + 53048320); // 6815744
  unsigned short* vt      = (unsigned short*)(ws + 59864064); // 6815744
  unsigned short* ob      = (unsigned short*)(ws + 66679808); // 6815744 -> 73495552

  hipLaunchKernelGGL(k_cvt3, dim3(12288), dim3(256), 0, stream, x, wqkv, wproj,
                     x_bf, wqkv_bf, wproj_bf);
  hipLaunchKernelGGL(k_mean_part, dim3(256), dim3(256), 0, stream, x, meanpart);
  hipLaunchKernelGGL(k_mean_reduce, dim3(8), dim3(256), 0, stream, meanpart, mean);
  hipLaunchKernelGGL(k_mse_base, dim3(8192), dim3(256), 0, stream, x, cached, mean, mse, out);
  hipLaunchKernelGGL(k_topk, dim3(BQ), dim3(1024), 0, stream, mse, idx_sel);
  hipLaunchKernelGGL((k_gemm<0>), dim3(26 * 24), dim3(256), 0, stream,
                     x_bf, wqkv_bf, idx_sel, qkv, (float*)nullptr,
                     (const float*)nullptr, (const float*)nullptr);
  hipLaunchKernelGGL(k_normrope, dim3(26 * 16 * BQ), dim3(256), 0, stream,
                     qkv, idx_sel, qbias, vbias, sml, rope, qo, ko, vt);
  hipLaunchKernelGGL(k_attn, dim3(13, BQ * NHQ, 2), dim3(256), 0, stream,
                     qo, ko, vt, sml, pO, pl);
  hipLaunchKernelGGL(k_comb, dim3(13312), dim3(256), 0, stream, pO, pl, ob);
  hipLaunchKernelGGL((k_gemm<1>), dim3(26 * 8), dim3(256), 0, stream,
                     ob, wproj_bf, idx_sel, (unsigned short*)nullptr, out, x, bproj);
}